// Round 6
// baseline (10877.571 us; speedup 1.0000x reference)
//
#include <hip/hip_runtime.h>
#include <cstdint>
#include <cstddef>

// Decoder (DA-RNN): B=512, T=256, E=D=256.
// Round 6: 512 threads per batch row (grid 512x512, launch_bounds(512,4) ->
// 16 waves/CU, double R5) with all per-thread work halved: q GEMV j-split
// (lane-pair shfl combine), gates GEMV gate-pair split, score e-half split
// (lane-pair shfl combine), Ph resident = 16 named half8 (64 VGPR).
// Anti-phase-lock: wg parity swaps position of the load-heavy gates GEMV
// so co-resident wgs overlap loads with VALU. 3 barriers/step.
// Gates weight layout is dword-clean (all half2 extractions free).

typedef _Float16 half8 __attribute__((ext_vector_type(8)));
typedef _Float16 half2v __attribute__((ext_vector_type(2)));

__device__ __forceinline__ float rcpf_(float x) { return __builtin_amdgcn_rcpf(x); }
__device__ __forceinline__ float sigmoidf_(float x) { return rcpf_(1.f + __expf(-x)); }
__device__ __forceinline__ float tanhf_(float x) { return 1.f - 2.f * rcpf_(1.f + __expf(2.f * x)); }

#if defined(__has_builtin)
#if __has_builtin(__builtin_amdgcn_fdot2)
#define HAS_FDOT2 1
#endif
#endif
#ifndef HAS_FDOT2
#define HAS_FDOT2 0
#endif

__device__ __forceinline__ float fdot2_(half2v a, half2v b, float c) {
#if HAS_FDOT2
  return __builtin_amdgcn_fdot2(a, b, c, false);
#else
  return fmaf((float)a[0], (float)b[0], fmaf((float)a[1], (float)b[1], c));
#endif
}

// ---------------- prep kernels ----------------

// wT[e*256+f] = attn_w1[f*768 + 512 + e]   (transposed w1_enc, fp32)
__global__ void k_prep_wT(const float* __restrict__ w1, float* __restrict__ wT) {
  int id = blockIdx.x * 256 + threadIdx.x;
  int e = id >> 8, f = id & 255;
  wT[id] = w1[f * 768 + 512 + e];
}

// w1hcP[(c*512 + e*2 + jh)*8 + m] = w1[e*768 + jh*256 + c*8 + m]  (fp16)
// k_scan thread tid=e*2+jh reads chunk c as contiguous 16B, coalesced.
__global__ void k_prep_w1hcP(const float* __restrict__ w1, _Float16* __restrict__ o) {
  int id = blockIdx.x * 256 + threadIdx.x;  // 131072 total
  int m = id & 7, lane = (id >> 3) & 511, c = id >> 12;
  int e = lane >> 1, jh = lane & 1;
  o[id] = (_Float16)w1[e * 768 + jh * 256 + c * 8 + m];
}

// whh6[(u*512 + tid)*8 + m]: tid=(k | gp<<8); m -> jps=m>>2, gs=(m>>1)&1, r=m&1
//   value = W_hh[((gp*2+gs)*256 + k)*256 + (u*4 + jps*2 + r)]
// All half2 extractions in k_scan are dword-aligned (free).
__global__ void k_prep_whh6(const float* __restrict__ whh, _Float16* __restrict__ o) {
  int id = blockIdx.x * 256 + threadIdx.x;  // 262144 total
  int m = id & 7, t = (id >> 3) & 511, u = id >> 12;
  int k = t & 255, gp = t >> 8;
  int jps = m >> 2, gs = (m >> 1) & 1, r = m & 1;
  int gate = gp * 2 + gs;
  int j = u * 4 + jps * 2 + r;
  o[id] = (_Float16)whh[(gate * 256 + k) * 256 + j];
}

// Fused: enc_proj GEMM + bias -> P=exp(2*encp) fp16 [b][e/8][t][e%8];
// also xh (x fp16 [b][t][e]) and xf[b*256+t] = x[b,t,:].fcw.
__global__ __launch_bounds__(256) void k_encp(const float* __restrict__ x,
                                              const float* __restrict__ wT,
                                              const float* __restrict__ b1,
                                              const float* __restrict__ fcw,
                                              _Float16* __restrict__ Ph2,
                                              _Float16* __restrict__ xh,
                                              float* __restrict__ xf) {
  __shared__ __align__(16) float xl[16][256];
  __shared__ float fw[256];
  __shared__ float part[16][17];
  const int tid = threadIdx.x;
  const int m0 = blockIdx.x * 16;
  fw[tid] = fcw[tid];
#pragma unroll
  for (int r = 0; r < 16; ++r) xl[r][tid] = x[(size_t)(m0 + r) * 256 + tid];
  __syncthreads();
#pragma unroll
  for (int r = 0; r < 16; ++r) xh[(size_t)(m0 + r) * 256 + tid] = (_Float16)xl[r][tid];
  {
    int r = tid >> 4, p = tid & 15;
    float s = 0.f;
#pragma unroll
    for (int u = 0; u < 16; ++u) s = fmaf(xl[r][p * 16 + u], fw[p * 16 + u], s);
    part[r][p] = s;
  }
  __syncthreads();
  if (tid < 16) {
    float t = 0.f;
#pragma unroll
    for (int p2 = 0; p2 < 16; ++p2) t += part[tid][p2];
    xf[m0 + tid] = t;
  }
  float acc[16];
#pragma unroll
  for (int r = 0; r < 16; ++r) acc[r] = 0.f;
  for (int e = 0; e < 256; e += 4) {
    float w0 = wT[(e + 0) * 256 + tid];
    float w1_ = wT[(e + 1) * 256 + tid];
    float w2_ = wT[(e + 2) * 256 + tid];
    float w3_ = wT[(e + 3) * 256 + tid];
#pragma unroll
    for (int r = 0; r < 16; ++r) {
      float4 xv = *reinterpret_cast<const float4*>(&xl[r][e]);
      acc[r] = fmaf(xv.x, w0, acc[r]);
      acc[r] = fmaf(xv.y, w1_, acc[r]);
      acc[r] = fmaf(xv.z, w2_, acc[r]);
      acc[r] = fmaf(xv.w, w3_, acc[r]);
    }
  }
  float bb = b1[tid];
  const int e = tid;
#pragma unroll
  for (int r = 0; r < 16; ++r) {
    int m = m0 + r, b = m >> 8, t = m & 255;
    float p = __expf(2.f * (acc[r] + bb));
    Ph2[((size_t)(b * 32 + (e >> 3)) * 256 + t) * 8 + (e & 7)] = (_Float16)p;
  }
}

// ---------------- the scan ----------------
// grid 512 x 512 threads; wg owns ONE batch row; 256 steps; 3 barriers/step.
__global__ __launch_bounds__(512, 4) void k_scan(
    const _Float16* __restrict__ Ph2, const _Float16* __restrict__ xh,
    const _Float16* __restrict__ w1hcP, const _Float16* __restrict__ whh6,
    const float* __restrict__ xf, const float* __restrict__ y_hist,
    const float* __restrict__ w2g, const float* __restrict__ Wih,
    const float* __restrict__ bih, const float* __restrict__ bhh,
    const float* __restrict__ fcw, const float* __restrict__ fcb,
    const float* __restrict__ fcfw, const float* __restrict__ fcfb,
    float* __restrict__ out) {
  __shared__ __align__(16) _Float16 hcH[512];  // [ h(256) | c(256) ] fp16
  __shared__ __align__(16) float Qs[256];      // exp(2q)
  __shared__ __align__(16) float ealpha[256];
  __shared__ __align__(16) float w2l[256];
  __shared__ __align__(16) float xfL[256];
  __shared__ __align__(16) float yhL[256];
  __shared__ __align__(16) float gpartG[256];
  __shared__ __align__(16) float gpartO[256];
  __shared__ __align__(16) float cpart[8][256];
  __shared__ float redA[8], redB[8];

  const int tid = threadIdx.x;          // 0..511
  const int wv = tid >> 6;              // wave 0..7
  const int lane = tid & 63;
  const int b = blockIdx.x;
  const int parity = (b ^ (b >> 8)) & 1;

  // ---- init ----
  hcH[tid] = (_Float16)0.f;
  if (tid < 256) {
    w2l[tid] = w2g[tid];
    xfL[tid] = xf[(size_t)b * 256 + tid];
    yhL[tid] = y_hist[(size_t)b * 256 + tid];
  }
  const int tt = tid & 255;
  // per-thread LSTM row constants (used by tid<256 in pointwise)
  float wihR0 = Wih[tt],       wihR1 = Wih[256 + tt];
  float wihR2 = Wih[512 + tt], wihR3 = Wih[768 + tt];
  float bR0 = bih[tt] + bhh[tt];
  float bR1 = bih[256 + tt] + bhh[256 + tt];
  float bR2 = bih[512 + tt] + bhh[512 + tt];
  float bR3 = bih[768 + tt] + bhh[768 + tt];
  __syncthreads();
  float w2sum = 0.f;
  for (int e2 = 0; e2 < 256; ++e2) w2sum += w2l[e2];
  const float fcb0 = fcb[0];
  const float fcwy = fcw[256];

  // ---- per-phase thread mappings ----
  // q GEMV: tid = e*2 + jh
  const int jh = tid & 1;
  const half8* wq = reinterpret_cast<const half8*>(w1hcP) + tid;  // wq[c*512]
  const half8* hh8 = reinterpret_cast<const half8*>(&hcH[0]) + jh * 32;  // chunk c
  // gates GEMV: tid = k | gp<<8
  const int gp = tid >> 8;
  const half8* wg6 = reinterpret_cast<const half8*>(whh6) + tid;  // wg6[u*512]
  // score: tid = tS*2 + eh
  const int tS = tid >> 1, eh = tid & 1;
  const half8* prow = reinterpret_cast<const half8*>(Ph2) +
                      ((size_t)b * 32 + eh * 16) * 256 + tS;

  // ---- Ph resident: 16 NAMED half8 (64 VGPRs), step-invariant ----
#define LDP(N) half8 s##N = prow[(N) * 256]
  LDP(0); LDP(1); LDP(2); LDP(3); LDP(4); LDP(5); LDP(6); LDP(7);
  LDP(8); LDP(9); LDP(10); LDP(11); LDP(12); LDP(13); LDP(14); LDP(15);
#undef LDP

  float c_reg = 0.f, h_reg = 0.f;
  float rs0 = 0.f;
  float gA0 = 0.f, gA1 = 0.f;

  // gates GEMV: thread (k=tt, gp) accumulates gates {gp*2, gp*2+1} of cell k.
  auto gates_gemv = [&]() {
    gA0 = 0.f; gA1 = 0.f;
    const uint2* hq = reinterpret_cast<const uint2*>(&hcH[0]);
#pragma unroll 8
    for (int u = 0; u < 64; ++u) {
      half8 wv8 = wg6[u * 512];
      uint2 hh = hq[u];
      half2v hp0 = __builtin_bit_cast(half2v, hh.x);
      half2v hp1 = __builtin_bit_cast(half2v, hh.y);
      half2v m01 = __builtin_shufflevector(wv8, wv8, 0, 1);
      half2v m23 = __builtin_shufflevector(wv8, wv8, 2, 3);
      half2v m45 = __builtin_shufflevector(wv8, wv8, 4, 5);
      half2v m67 = __builtin_shufflevector(wv8, wv8, 6, 7);
      gA0 = fdot2_(m01, hp0, gA0);
      gA1 = fdot2_(m23, hp0, gA1);
      gA0 = fdot2_(m45, hp1, gA0);
      gA1 = fdot2_(m67, hp1, gA1);
    }
    if (gp) { gpartG[tt] = gA0; gpartO[tt] = gA1; }
  };

#pragma unroll 1
  for (int s = 0; s < 256; ++s) {
    // ======== q GEMV: thread (e, jh) covers j in [jh*256, jh*256+256) ========
    float qa = 0.f;
#pragma unroll 8
    for (int c = 0; c < 32; ++c) {
      half8 wv8 = wq[c * 512];
      half8 hv8 = hh8[c];
      half2v w0 = __builtin_shufflevector(wv8, wv8, 0, 1);
      half2v w1_ = __builtin_shufflevector(wv8, wv8, 2, 3);
      half2v w2_ = __builtin_shufflevector(wv8, wv8, 4, 5);
      half2v w3_ = __builtin_shufflevector(wv8, wv8, 6, 7);
      half2v h0 = __builtin_shufflevector(hv8, hv8, 0, 1);
      half2v h1 = __builtin_shufflevector(hv8, hv8, 2, 3);
      half2v h2 = __builtin_shufflevector(hv8, hv8, 4, 5);
      half2v h3 = __builtin_shufflevector(hv8, hv8, 6, 7);
      qa = fdot2_(w0, h0, qa);
      qa = fdot2_(w1_, h1, qa);
      qa = fdot2_(w2_, h2, qa);
      qa = fdot2_(w3_, h3, qa);
    }
    qa += __shfl_xor(qa, 1);
    if (jh == 0) Qs[tS] = __expf(2.f * qa);  // tS == e for jh==0

    if (!parity) gates_gemv();
    __syncthreads();  // B1: Qs (and X-variant gparts) visible

    // ======== score: thread (t=tS, e-half eh), Ph from registers ========
    float sacc = 0.f;
    {
      const float4* q4 = reinterpret_cast<const float4*>(&Qs[0]) + eh * 32;
      const float4* w4 = reinterpret_cast<const float4*>(&w2l[0]) + eh * 32;
#define SCCHUNK(C, PV)                                                   \
      {                                                                  \
        float4 qva = q4[2 * (C)], qvb = q4[2 * (C) + 1];                 \
        float4 wa = w4[2 * (C)], wb = w4[2 * (C) + 1];                   \
        float x0 = fmaf((float)PV[0], qva.x, 1.f);                       \
        float x1 = fmaf((float)PV[1], qva.y, 1.f);                       \
        float x2 = fmaf((float)PV[2], qva.z, 1.f);                       \
        float x3 = fmaf((float)PV[3], qva.w, 1.f);                       \
        float x4 = fmaf((float)PV[4], qvb.x, 1.f);                       \
        float x5 = fmaf((float)PV[5], qvb.y, 1.f);                       \
        float x6 = fmaf((float)PV[6], qvb.z, 1.f);                       \
        float x7 = fmaf((float)PV[7], qvb.w, 1.f);                       \
        sacc = fmaf(fmaf(wa.x, x1, wa.y * x0), rcpf_(x0 * x1), sacc);    \
        sacc = fmaf(fmaf(wa.z, x3, wa.w * x2), rcpf_(x2 * x3), sacc);    \
        sacc = fmaf(fmaf(wb.x, x5, wb.y * x4), rcpf_(x4 * x5), sacc);    \
        sacc = fmaf(fmaf(wb.z, x7, wb.w * x6), rcpf_(x6 * x7), sacc);    \
      }
      SCCHUNK(0, s0) SCCHUNK(1, s1) SCCHUNK(2, s2) SCCHUNK(3, s3)
      SCCHUNK(4, s4) SCCHUNK(5, s5) SCCHUNK(6, s6) SCCHUNK(7, s7)
      SCCHUNK(8, s8) SCCHUNK(9, s9) SCCHUNK(10, s10) SCCHUNK(11, s11)
      SCCHUNK(12, s12) SCCHUNK(13, s13) SCCHUNK(14, s14) SCCHUNK(15, s15)
#undef SCCHUNK
    }
    sacc += __shfl_xor(sacc, 1);  // combine e-halves (lane pair)
    float sc = w2sum - 2.f * sacc;
    float ea = __expf(sc);  // |sc| bounded ~15, fp32-safe (validated R2-R5)
    if (eh == 0) ealpha[tS] = ea;
    float ef = ea * xfL[tS];
    float es = ea;
#pragma unroll
    for (int off = 32; off > 0; off >>= 1) {
      es += __shfl_xor(es, off);
      ef += __shfl_xor(ef, off);
    }
    if (lane == 0) { redA[wv] = es; redB[wv] = ef; }  // sums = 2x true (dups)
    if (parity) gates_gemv();
    __syncthreads();  // B2: reductions (and Y-variant gparts) visible

    // ======== y_tilde + LSTM pointwise (threads 0..255, waves 0-3) ========
    if (tid < 256) {
      float es2 = redA[0] + redA[1] + redA[2] + redA[3] +
                  redA[4] + redA[5] + redA[6] + redA[7];
      float ef2 = redB[0] + redB[1] + redB[2] + redB[3] +
                  redB[4] + redB[5] + redB[6] + redB[7];
      rs0 = rcpf_(es2);  // NOTE: es2 = 2*sum(ea); true 1/sum = 2*rs0
      float yt = ef2 * rs0 + fmaf(yhL[s], fcwy, fcb0);  // ef2/es2 == ef/es
      float gi = fmaf(yt, wihR0, bR0 + gA0);
      float gf = fmaf(yt, wihR1, bR1 + gA1);
      float gc = fmaf(yt, wihR2, bR2 + gpartG[tt]);
      float go = fmaf(yt, wihR3, bR3 + gpartO[tt]);
      float iv = sigmoidf_(gi), fv = sigmoidf_(gf), gv = tanhf_(gc), ov = sigmoidf_(go);
      c_reg = fmaf(fv, c_reg, iv * gv);
      h_reg = ov * tanhf_(c_reg);
      hcH[tt] = (_Float16)h_reg;
      hcH[256 + tt] = (_Float16)c_reg;
    }
    __syncthreads();  // B3: h,c visible
  }

  // ---- final context (ealpha/rs0 from step 255), threads 0..255 ----
  if (tid < 256) {
    const int t8 = tt >> 5, l5 = tt & 31;
    const half8* xrow = reinterpret_cast<const half8*>(xh) + ((size_t)b * 256 + t8 * 32) * 32;
    float ac[8];
#pragma unroll
    for (int m = 0; m < 8; ++m) ac[m] = 0.f;
#pragma unroll 4
    for (int it = 0; it < 32; ++it) {
      float al = ealpha[t8 * 32 + it];
      half8 xv = xrow[it * 32 + l5];
#pragma unroll
      for (int m = 0; m < 8; ++m) ac[m] = fmaf(al, (float)xv[m], ac[m]);
    }
    *reinterpret_cast<float4*>(&cpart[t8][l5 * 8]) = *reinterpret_cast<float4*>(&ac[0]);
    *reinterpret_cast<float4*>(&cpart[t8][l5 * 8 + 4]) = *reinterpret_cast<float4*>(&ac[4]);
  }
  __syncthreads();
  float o0 = 0.f, o1 = 0.f;
  if (tid < 256) {
    float cv = 0.f;
#pragma unroll
    for (int u = 0; u < 8; ++u) cv += cpart[u][tt];
    cv *= 2.f * rs0;  // rs0 = rcp(2*sum) -> true scale
    o0 = h_reg * fcfw[tt] + cv * fcfw[256 + tt];
    o1 = h_reg * fcfw[512 + tt] + cv * fcfw[768 + tt];
#pragma unroll
    for (int off = 32; off > 0; off >>= 1) {
      o0 += __shfl_xor(o0, off);
      o1 += __shfl_xor(o1, off);
    }
  }
  __syncthreads();
  if (lane == 0 && tid < 256) { redA[wv] = o0; redB[wv] = o1; }
  __syncthreads();
  if (tid < 2) {
    const float* r = (tid == 0) ? redA : redB;
    out[b * 2 + tid] = fcfb[tid] + r[0] + r[1] + r[2] + r[3];
  }
}

extern "C" void kernel_launch(void* const* d_in, const int* in_sizes, int n_in,
                              void* d_out, int out_size, void* d_ws, size_t ws_size,
                              hipStream_t stream) {
  (void)in_sizes; (void)n_in; (void)out_size; (void)ws_size;
  const float* x    = (const float*)d_in[0];
  const float* yh   = (const float*)d_in[1];
  const float* w1   = (const float*)d_in[2];
  const float* b1   = (const float*)d_in[3];
  const float* w2   = (const float*)d_in[4];
  /* d_in[5] attn_b2: softmax-invariant, unused */
  const float* Wih  = (const float*)d_in[6];
  const float* Whh  = (const float*)d_in[7];
  const float* bih  = (const float*)d_in[8];
  const float* bhh  = (const float*)d_in[9];
  const float* fcw  = (const float*)d_in[10];
  const float* fcb  = (const float*)d_in[11];
  const float* fcfw = (const float*)d_in[12];
  const float* fcfb = (const float*)d_in[13];
  float* out = (float*)d_out;

  char* ws = (char*)d_ws;
  _Float16* Ph2   = (_Float16*)(ws);                      // 67108864 B
  _Float16* xh    = (_Float16*)(ws + (size_t)67108864);   // 67108864 B
  float*    wT    = (float*)   (ws + (size_t)134217728);  // 262144 B
  _Float16* w1hcP = (_Float16*)(ws + (size_t)134479872);  // 262144 B
  _Float16* whh6  = (_Float16*)(ws + (size_t)134742016);  // 524288 B
  float*    xf    = (float*)   (ws + (size_t)135266304);  // 524288 B
  // total: 135790592 B (~129.5 MB)

  k_prep_wT   <<<256,  256, 0, stream>>>(w1, wT);
  k_prep_w1hcP<<<512,  256, 0, stream>>>(w1, w1hcP);
  k_prep_whh6 <<<1024, 256, 0, stream>>>(Whh, whh6);
  k_encp      <<<8192, 256, 0, stream>>>(x, wT, b1, fcw, Ph2, xh, xf);
  k_scan      <<<512,  512, 0, stream>>>(Ph2, xh, w1hcP, whh6, xf, yh, w2, Wih,
                                         bih, bhh, fcw, fcb, fcfw, fcfb, out);
}